// Round 15
// baseline (65.447 us; speedup 1.0000x reference)
//
#include <hip/hip_runtime.h>

// Fully-fused 4-level db4 wavedec ('symmetric'), faithful to the JAX/pywt reference.
// x: [B=64, L=4096, C=32] f32. Out flat: cA4,cD4,cD3,cD2,cD1 each [B,C,len].
// lens: 4096 -> 2051 -> 1029 -> 518 -> 262.
// r15: NCHB=16 (half of each sample line per block) => x staging is FULLY
// coalesced (4 lanes = one 64B half-line, every transaction 100% used);
// chip-wide x-ingest L1/L2 transactions drop 3.4x vs NCHB=4 (the largest
// non-overlapping cost in the r14 diagnostic: exec ~25us, overhead ~5us).
// Block = (batch, 16-ch half, tile of 17 cA4); 2048 blocks x 384 thr.
// LDS 58 KB (cd2..ca4 overlaid into dead bx region) -> 2 blocks/CU.

#define NT 384
#define NCHB 16

// Window-row pitches (floats), == 2 mod 4 (pitch/2 odd): b64 window reads
// spread the 16 c-lanes over 16 distinct bank-pairs (4 lanes/pair = free).
#define PX 378   // x span <= 362 (+13 margins = 375)
#define PB1 194  // l1 span <= 178 (+13 = 191)
#define PB2 102  // l2 span <= 86  (+13 = 99)
#define PB3 54   // l3 span <= 40  (+13 = 53)
// Output staging pitches (even).
#define CDP1 178 // cd1 span <= 178
#define CDP2 86  // cd2 span <= 86
#define CDP3 40  // cd3 span <= 40
#define CDP4 18  // cd4 span <= 17
#define CAP4 18  // ca4 span <= 17

#define L0C 4096
#define L1C 2051
#define L2C 1029
#define L3C 518
#define L4C 262
#define SC 2048

// All output offsets fit in int (out_size ~ 8.44M floats).
#define OFF_CD4 (SC * L4C)
#define OFF_CD3 (2 * SC * L4C)
#define OFF_CD2 (OFF_CD3 + SC * L3C)
#define OFF_CD1 (OFF_CD2 + SC * L2C)

__device__ __forceinline__ void filt8(
    const float w0, const float w1, const float w2, const float w3,
    const float w4, const float w5, const float w6, const float w7,
    float& a, float& d) {
    // db4 correlation kernels (dec_lo reversed = _H; dec_hi reversed), split trees.
    constexpr float FLO[8] = {
        0.23037781330885523f,  0.7148465705525415f,  0.6308807679295904f,
        -0.02798376941698385f, -0.18703481171888114f, 0.030841381835986965f,
        0.032883011666982945f, -0.010597401784997278f};
    constexpr float FHI[8] = {
        -0.010597401784997278f, -0.032883011666982945f, 0.030841381835986965f,
        0.18703481171888114f,  -0.02798376941698385f,  -0.6308807679295904f,
        0.7148465705525415f,   -0.23037781330885523f};
    float a0 = FLO[0] * w0;
    a0 = fmaf(FLO[1], w1, a0); a0 = fmaf(FLO[2], w2, a0); a0 = fmaf(FLO[3], w3, a0);
    float a1 = FLO[4] * w4;
    a1 = fmaf(FLO[5], w5, a1); a1 = fmaf(FLO[6], w6, a1); a1 = fmaf(FLO[7], w7, a1);
    a = a0 + a1;
    float d0 = FHI[0] * w0;
    d0 = fmaf(FHI[1], w1, d0); d0 = fmaf(FHI[2], w2, d0); d0 = fmaf(FHI[3], w3, d0);
    float d1 = FHI[4] * w4;
    d1 = fmaf(FHI[5], w5, d1); d1 = fmaf(FHI[6], w6, d1); d1 = fmaf(FHI[7], w7, d1);
    d = d0 + d1;
}

// One even-aligned run of R outputs (R even). Full runs tile the span exactly;
// the one remainder slot does an even-clamped run (+ scalar tail if span odd);
// all higher slots return immediately (no duplicate work).
template <int R, bool MG, bool LAST>
__device__ __forceinline__ void level_run(
    const float* __restrict__ src, int PS, int srclo,
    float* __restrict__ dst, int PD, int DL,
    int lo, int hi,
    float* __restrict__ cdbuf, int CDP,
    float* __restrict__ cabuf,
    int c, int slot) {
    static_assert((R & 1) == 0, "R must be even");
    const int span = hi - lo;
    const int nrun = span / R;
    bool tail = false;
    int i0;
    if (slot < nrun) {
        i0 = lo + slot * R;
    } else if (slot == nrun && nrun * R < span) {
        i0 = lo + ((span - R) & ~1);
        tail = (span & 1) != 0;
    } else {
        return;
    }

    const float* rowb = src + c * PS;
    const float2* row2 = reinterpret_cast<const float2*>(rowb);
    const int p = i0 - (srclo >> 1);  // sample t at word t-srclo+6; first tap t=2*i0-6
    float2 f0 = row2[p], f1 = row2[p + 1], f2 = row2[p + 2];

    float* dbase = LAST ? nullptr : dst + c * PD;
    float* cdbase = cdbuf + c * CDP;
    float* cabase = LAST ? cabuf + c * CAP4 : nullptr;

    float ap = 0.f, dp = 0.f;
#pragma unroll
    for (int r = 0; r < R; ++r) {
        const float2 f3 = row2[p + 3 + r];
        const int i = i0 + r;
        float a, d;
        filt8(f0.x, f0.y, f1.x, f1.y, f2.x, f2.y, f3.x, f3.y, a, d);
        if (r & 1) {
            const int w = i - 1 - lo;  // even
            if constexpr (!LAST)
                *reinterpret_cast<float2*>(dbase + w + 6) = make_float2(ap, a);
            else
                *reinterpret_cast<float2*>(cabase + w) = make_float2(ap, a);
            *reinterpret_cast<float2*>(cdbase + w) = make_float2(dp, d);
        } else {
            ap = a; dp = d;
        }
        if constexpr (MG && !LAST) {
            // reflection margins for the next level (boundary tiles only)
            if (lo == 0 && i < 6) dbase[5 - i] = a;
            if (hi == DL && i >= DL - 7) dbase[(2 * DL - 1 - i) - lo + 6] = a;
        }
        f0 = f1; f1 = f2; f2 = f3;
    }
    if (tail) {
        const int i = hi - 1;
        const float* s = rowb + 6 - srclo;  // s[t] = sample t
        float a, d;
        filt8(s[2*i-6], s[2*i-5], s[2*i-4], s[2*i-3],
              s[2*i-2], s[2*i-1], s[2*i],   s[2*i+1], a, d);
        if constexpr (!LAST) {
            dbase[i - lo + 6] = a;
            if constexpr (MG) {
                if (hi == DL && i >= DL - 7) dbase[(2 * DL - 1 - i) - lo + 6] = a;
            }
        } else {
            cabase[i - lo] = a;
        }
        cdbase[i - lo] = d;
    }
}

// Dump staged rows to global: float2 LDS reads, coalesced dword stores.
// (ownLo - bufLo) is even at every call site.
__device__ __forceinline__ void dump_rows(
    const float* __restrict__ buf, int pitch, int bufLo,
    float* __restrict__ gbase, int rowLen, int ownLo, int ownHi, int tid) {
    const int span = ownHi - ownLo;
    const int n2 = span >> 1;
    const int off = ownLo - bufLo;
#pragma unroll
    for (int c2 = 0; c2 < NCHB; ++c2) {
        const float2* s2 = reinterpret_cast<const float2*>(buf + c2 * pitch + off);
        float* g = gbase + c2 * rowLen + ownLo;
        for (int k = tid; k < n2; k += NT) {
            const float2 v = s2[k];
            g[2 * k] = v.x;
            g[2 * k + 1] = v.y;
        }
        if ((span & 1) && tid == 0) g[span - 1] = buf[c2 * pitch + off + span - 1];
    }
}

template <bool MG>
__device__ __forceinline__ void cascade(
    const float* bx, float* b1, float* b2, float* b3,
    float* cd1, float* cd2, float* cd3, float* cd4, float* ca4,
    float* __restrict__ out, int sigB, int tile, int c, int slot, int tid,
    int lox, int lo1, int hi1, int lo2, int hi2, int lo3, int hi3,
    int lo4, int hi4) {
    // owned (exclusive, tile-partitioned) detail ranges (16 tiles)
    const int o1lo = tile ? 136 * tile - 20 : 0;
    const int o1hi = (tile == 15) ? L1C : 136 * tile + 116;
    const int o2lo = tile ? 68 * tile - 8 : 0;
    const int o2hi = (tile == 15) ? L2C : 68 * tile + 60;
    const int o3lo = tile ? 34 * tile - 2 : 0;
    const int o3hi = (tile == 15) ? L3C : 34 * tile + 32;

    level_run<8, MG, false>(bx, PX, lox, b1, PB1, L1C, lo1, hi1, cd1, CDP1,
                            nullptr, c, slot);
    __syncthreads();
    // bx is dead from here on: cd2/cd3/cd4/ca4 overlay its region.

    dump_rows(cd1, CDP1, lo1, out + OFF_CD1 + sigB * L1C, L1C, o1lo, o1hi, tid);
    level_run<4, MG, false>(b1, PB1, lo1, b2, PB2, L2C, lo2, hi2, cd2, CDP2,
                            nullptr, c, slot);
    __syncthreads();

    dump_rows(cd2, CDP2, lo2, out + OFF_CD2 + sigB * L2C, L2C, o2lo, o2hi, tid);
    level_run<2, MG, false>(b2, PB2, lo2, b3, PB3, L3C, lo3, hi3, cd3, CDP3,
                            nullptr, c, slot);
    __syncthreads();

    dump_rows(cd3, CDP3, lo3, out + OFF_CD3 + sigB * L3C, L3C, o3lo, o3hi, tid);
    level_run<2, false, true>(b3, PB3, lo3, nullptr, 0, L4C, lo4, hi4, cd4, CDP4,
                              ca4, c, slot);
    __syncthreads();

    dump_rows(cd4, CDP4, lo4, out + OFF_CD4 + sigB * L4C, L4C, lo4, hi4, tid);
    dump_rows(ca4, CAP4, lo4, out + sigB * L4C, L4C, lo4, hi4, tid);
}

__global__ __launch_bounds__(NT, 3) void fused_dwt_kernel(
    const float* __restrict__ x, float* __restrict__ out) {
    __shared__ __align__(16) float bxpool[NCHB * PX];
    __shared__ __align__(16) float b1[NCHB * PB1];
    __shared__ __align__(16) float b2[NCHB * PB2];
    __shared__ __align__(16) float b3[NCHB * PB3];
    __shared__ __align__(16) float cd1[NCHB * CDP1];
    // cd2/cd3/cd4/ca4 overlay the dead bx region after level 1 (16*162 <= 16*378).
    float* bx  = bxpool;
    float* cd2 = bxpool;
    float* cd3 = bxpool + NCHB * CDP2;
    float* cd4 = bxpool + NCHB * (CDP2 + CDP3);
    float* ca4 = bxpool + NCHB * (CDP2 + CDP3 + CDP4);

    // XCD swizzle: 2048 blocks = 8 XCDs x 256 contiguous works; consecutive
    // works = channel-half siblings + tiles of one batch -> one XCD's L2.
    const int bid = blockIdx.x;
    const int work = (bid & 7) * 256 + (bid >> 3);
    const int cg = work & 1;            // channel half 0..1 (16 ch each)
    const int tile = (work >> 1) & 15;  // cA4 tile 0..15
    const int b = work >> 5;            // batch 0..63

    const int tid = threadIdx.x;
    const int c = tid & 15;
    const int slot = tid >> 4;  // 0..23
    const int c0 = cg * 16;
    const int sigB = b * 32 + c0;

    const int lo4 = 17 * tile, hi4 = min(L4C, lo4 + 17);
    const int lo3 = max(0, 2 * lo4 - 6), hi3 = min(L3C, 2 * hi4);
    const int lo2 = max(0, 2 * lo3 - 6), hi2 = min(L2C, 2 * hi3);
    const int lo1 = max(0, 2 * lo2 - 6), hi1 = min(L1C, 2 * hi2);
    const int lox = max(0, 2 * lo1 - 6), hix = min(L0C, 2 * hi1);

    // ---- stage x: FULLY COALESCED. 4 consecutive lanes read the 4 float4
    // quarters of one sample's 64B half-line; each lane scatters its 4
    // channels into 4 transposed LDS rows (2 lanes/bank = conflict-free). ----
    const float* xb = x + b * (L0C * 32) + c0;
    const bool mgl = (lox == 0), mgr = (hix == L0C);
    const int nq = (hix - lox) << 2;
    for (int q = tid; q < nq; q += NT) {
        const int s = q >> 2;        // sample within span
        const int t = lox + s;
        const float4 v = *reinterpret_cast<const float4*>(xb + t * 32 + (q & 3) * 4);
        const float vv[4] = {v.x, v.y, v.z, v.w};
        const int r0 = (q & 3) * 4;  // first of this lane's 4 channel rows
#pragma unroll
        for (int j = 0; j < 4; ++j) {
            float* row = bx + (r0 + j) * PX;
            row[s + 6] = vv[j];
            if (mgl && t < 6) row[5 - t] = vv[j];
            if (mgr && t >= L0C - 7) row[(2 * L0C - 1 - t) - lox + 6] = vv[j];
        }
    }
    __syncthreads();

    if (tile == 0 || tile == 15)
        cascade<true>(bx, b1, b2, b3, cd1, cd2, cd3, cd4, ca4, out, sigB, tile,
                      c, slot, tid, lox, lo1, hi1, lo2, hi2, lo3, hi3, lo4, hi4);
    else
        cascade<false>(bx, b1, b2, b3, cd1, cd2, cd3, cd4, ca4, out, sigB, tile,
                       c, slot, tid, lox, lo1, hi1, lo2, hi2, lo3, hi3, lo4, hi4);
}

extern "C" void kernel_launch(void* const* d_in, const int* in_sizes, int n_in,
                              void* d_out, int out_size, void* d_ws, size_t ws_size,
                              hipStream_t stream) {
    (void)in_sizes; (void)n_in; (void)d_ws; (void)ws_size; (void)out_size;
    const float* x = (const float*)d_in[0];
    float* out = (float*)d_out;
    fused_dwt_kernel<<<dim3(2048), dim3(NT), 0, stream>>>(x, out);
}

// Round 16
// 30.501 us; speedup vs baseline: 2.1457x; 2.1457x over previous
//
#include <hip/hip_runtime.h>

// Fully-fused 4-level db4 wavedec ('symmetric'), faithful to the JAX/pywt reference.
// x: [B=64, L=4096, C=32] f32. Out flat: cA4,cD4,cD3,cD2,cD1 each [B,C,len].
// lens: 4096 -> 2051 -> 1029 -> 518 -> 262.
// r16 "lean": r9 structure, but ALL outputs stored DIRECTLY to global from the
// compute runs (guarded scalar stores; L2 merges run-structured stores -- r3
// evidence: WRITE_SIZE stayed 33MB). No cd staging buffers, no dump phases,
// 3 barriers. LDS 19.3 KB -> 8 blocks/CU (32 waves). 4096 blocks x 256 thr.

#define NT 256
#define NCHB 4

// Window-row pitches (floats), == 2 mod 4 (pitch/2 odd): b64 accesses spread
// 4 lanes/bank-pair (the wave64 b64 minimum) for run strides R=6/4/2.
#define LPX 634  // x span <= 618 (+6 left, +7 right margins)
#define LP1 322  // l1 span <= 306
#define LP2 166  // l2 span <= 150
#define LP3 86   // l3 span <= 72

#define L0C 4096
#define L1C 2051
#define L2C 1029
#define L3C 518
#define L4C 262
#define SC 2048

// All output offsets fit in int (out_size ~ 8.44M floats).
#define OFF_CD4 (SC * L4C)
#define OFF_CD3 (2 * SC * L4C)
#define OFF_CD2 (OFF_CD3 + SC * L3C)
#define OFF_CD1 (OFF_CD2 + SC * L2C)

__device__ __forceinline__ void filt8(
    const float w0, const float w1, const float w2, const float w3,
    const float w4, const float w5, const float w6, const float w7,
    float& a, float& d) {
    // db4 correlation kernels (dec_lo reversed = _H; dec_hi reversed), split trees.
    constexpr float FLO[8] = {
        0.23037781330885523f,  0.7148465705525415f,  0.6308807679295904f,
        -0.02798376941698385f, -0.18703481171888114f, 0.030841381835986965f,
        0.032883011666982945f, -0.010597401784997278f};
    constexpr float FHI[8] = {
        -0.010597401784997278f, -0.032883011666982945f, 0.030841381835986965f,
        0.18703481171888114f,  -0.02798376941698385f,  -0.6308807679295904f,
        0.7148465705525415f,   -0.23037781330885523f};
    float a0 = FLO[0] * w0;
    a0 = fmaf(FLO[1], w1, a0); a0 = fmaf(FLO[2], w2, a0); a0 = fmaf(FLO[3], w3, a0);
    float a1 = FLO[4] * w4;
    a1 = fmaf(FLO[5], w5, a1); a1 = fmaf(FLO[6], w6, a1); a1 = fmaf(FLO[7], w7, a1);
    a = a0 + a1;
    float d0 = FHI[0] * w0;
    d0 = fmaf(FHI[1], w1, d0); d0 = fmaf(FHI[2], w2, d0); d0 = fmaf(FHI[3], w3, d0);
    float d1 = FHI[4] * w4;
    d1 = fmaf(FHI[5], w5, d1); d1 = fmaf(FHI[6], w6, d1); d1 = fmaf(FHI[7], w7, d1);
    d = d0 + d1;
}

// One even-aligned run of R outputs (R even). Full runs tile the span exactly;
// the one remainder slot does an even-clamped run (+ scalar tail if span odd);
// all higher slots return immediately. cd (and cA4) go STRAIGHT to global:
// gcd/gca are this channel's output rows; stores guarded to [ownLo, ownHi).
template <int R, bool MG, bool LAST>
__device__ __forceinline__ void level_run(
    const float* __restrict__ src, int PS, int srclo,
    float* __restrict__ dst, int PD, int DL,
    int lo, int hi,
    float* __restrict__ gcd, int ownLo, int ownHi,
    float* __restrict__ gca,
    int c, int slot) {
    static_assert((R & 1) == 0, "R must be even");
    const int span = hi - lo;
    const int nrun = span / R;
    bool tail = false;
    int i0;
    if (slot < nrun) {
        i0 = lo + slot * R;
    } else if (slot == nrun && nrun * R < span) {
        i0 = lo + ((span - R) & ~1);
        tail = (span & 1) != 0;
    } else {
        return;
    }

    const float* rowb = src + c * PS;
    const float2* row2 = reinterpret_cast<const float2*>(rowb);
    const int p = i0 - (srclo >> 1);  // sample t at word t-srclo+6; first tap t=2*i0-6
    float2 f0 = row2[p], f1 = row2[p + 1], f2 = row2[p + 2];

    float* dbase = LAST ? nullptr : dst + c * PD;

    float ap = 0.f;
#pragma unroll
    for (int r = 0; r < R; ++r) {
        const float2 f3 = row2[p + 3 + r];
        const int i = i0 + r;
        float a, d;
        filt8(f0.x, f0.y, f1.x, f1.y, f2.x, f2.y, f3.x, f3.y, a, d);
        if (i >= ownLo && i < ownHi) gcd[i] = d;   // direct global store
        if constexpr (!LAST) {
            if (r & 1)
                *reinterpret_cast<float2*>(dbase + (i - 1 - lo) + 6) =
                    make_float2(ap, a);
            else
                ap = a;
            if constexpr (MG) {
                // reflection margins for the next level (boundary tiles only)
                if (lo == 0 && i < 6) dbase[5 - i] = a;
                if (hi == DL && i >= DL - 7) dbase[(2 * DL - 1 - i) - lo + 6] = a;
            }
        } else {
            gca[i] = a;  // cA4 direct
        }
        f0 = f1; f1 = f2; f2 = f3;
    }
    if (tail) {
        const int i = hi - 1;
        const float* s = rowb + 6 - srclo;  // s[t] = sample t
        float a, d;
        filt8(s[2*i-6], s[2*i-5], s[2*i-4], s[2*i-3],
              s[2*i-2], s[2*i-1], s[2*i],   s[2*i+1], a, d);
        if (i >= ownLo && i < ownHi) gcd[i] = d;
        if constexpr (!LAST) {
            dbase[i - lo + 6] = a;
            if constexpr (MG) {
                if (hi == DL && i >= DL - 7) dbase[(2 * DL - 1 - i) - lo + 6] = a;
            }
        } else {
            gca[i] = a;
        }
    }
}

template <bool MG>
__device__ __forceinline__ void cascade(
    const float* bx, float* b1, float* b2, float* b3,
    float* __restrict__ out, int sigB, int tile, int c, int slot,
    int lox, int lo1, int hi1, int lo2, int hi2, int lo3, int hi3,
    int lo4, int hi4) {
    // owned (exclusive, tile-partitioned) detail ranges
    const int o1lo = tile ? 264 * tile - 34 : 0;
    const int o1hi = (tile == 7) ? L1C : 264 * tile + 230;
    const int o2lo = tile ? 132 * tile - 10 : 0;
    const int o2hi = (tile == 7) ? L2C : 132 * tile + 122;
    const int o3lo = tile ? 66 * tile - 2 : 0;
    const int o3hi = (tile == 7) ? L3C : 66 * tile + 64;

    const int sig = sigB + c;
    float* gcd1 = out + OFF_CD1 + sig * L1C;
    float* gcd2 = out + OFF_CD2 + sig * L2C;
    float* gcd3 = out + OFF_CD3 + sig * L3C;
    float* gcd4 = out + OFF_CD4 + sig * L4C;
    float* gca4 = out + sig * L4C;

    level_run<6, MG, false>(bx, LPX, lox, b1, LP1, L1C, lo1, hi1,
                            gcd1, o1lo, o1hi, nullptr, c, slot);
    __syncthreads();

    level_run<4, MG, false>(b1, LP1, lo1, b2, LP2, L2C, lo2, hi2,
                            gcd2, o2lo, o2hi, nullptr, c, slot);
    __syncthreads();

    level_run<2, MG, false>(b2, LP2, lo2, b3, LP3, L3C, lo3, hi3,
                            gcd3, o3lo, o3hi, nullptr, c, slot);
    __syncthreads();

    level_run<2, false, true>(b3, LP3, lo3, nullptr, 0, L4C, lo4, hi4,
                              gcd4, lo4, hi4, gca4, c, slot);
}

__global__ __launch_bounds__(NT, 8) void fused_dwt_kernel(
    const float* __restrict__ x, float* __restrict__ out) {
    __shared__ __align__(16) float bx[NCHB * LPX];
    __shared__ __align__(16) float b1[NCHB * LP1];
    __shared__ __align__(16) float b2[NCHB * LP2];
    __shared__ __align__(16) float b3[NCHB * LP3];

    // XCD swizzle: 4096 blocks = 8 XCDs x 512 contiguous works; the 8
    // channel-group siblings (consecutive works) share one XCD's L2.
    const int bid = blockIdx.x;
    const int work = (bid & 7) * 512 + (bid >> 3);
    const int cg = work & 7;           // channel group 0..7 (4 ch each)
    const int tile = (work >> 3) & 7;  // cA4 tile 0..7
    const int b = work >> 6;           // batch 0..63

    const int tid = threadIdx.x;
    const int c = tid & 3;
    const int slot = tid >> 2;  // 0..63
    const int c0 = cg * 4;
    const int sigB = b * 32 + c0;

    const int lo4 = 33 * tile, hi4 = min(L4C, lo4 + 33);
    const int lo3 = max(0, 2 * lo4 - 6), hi3 = min(L3C, 2 * hi4);
    const int lo2 = max(0, 2 * lo3 - 6), hi2 = min(L2C, 2 * hi3);
    const int lo1 = max(0, 2 * lo2 - 6), hi1 = min(L1C, 2 * hi2);
    const int lox = max(0, 2 * lo1 - 6), hix = min(L0C, 2 * hi1);

    // ---- stage x tile into transposed rows: one float4 covers the block's 4
    // channels; float2 pair writes per row (+ reflection margins) ----
    const float* xb = x + b * (L0C * 32) + c0;
    const int npair = (hix - lox) >> 1;
    for (int q = tid; q < npair; q += NT) {
        const int j = q << 1;
        const int t = lox + j;
        const float4 va = *reinterpret_cast<const float4*>(xb + t * 32);
        const float4 vb = *reinterpret_cast<const float4*>(xb + t * 32 + 32);
        const float av[4] = {va.x, va.y, va.z, va.w};
        const float bv[4] = {vb.x, vb.y, vb.z, vb.w};
#pragma unroll
        for (int hh = 0; hh < NCHB; ++hh)
            *reinterpret_cast<float2*>(bx + hh * LPX + 6 + j) =
                make_float2(av[hh], bv[hh]);
        if (lox == 0 && t < 6) {
#pragma unroll
            for (int hh = 0; hh < NCHB; ++hh) {
                bx[hh * LPX + 5 - t] = av[hh];
                if (t + 1 < 6) bx[hh * LPX + 4 - t] = bv[hh];
            }
        }
        if (hix == L0C && t + 1 >= L0C - 7) {
#pragma unroll
            for (int hh = 0; hh < NCHB; ++hh) {
                if (t >= L0C - 7) bx[hh * LPX + (2 * L0C - 1 - t) - lox + 6] = av[hh];
                bx[hh * LPX + (2 * L0C - 2 - t) - lox + 6] = bv[hh];
            }
        }
    }
    __syncthreads();

    if (tile == 0 || tile == 7)
        cascade<true>(bx, b1, b2, b3, out, sigB, tile, c, slot,
                      lox, lo1, hi1, lo2, hi2, lo3, hi3, lo4, hi4);
    else
        cascade<false>(bx, b1, b2, b3, out, sigB, tile, c, slot,
                       lox, lo1, hi1, lo2, hi2, lo3, hi3, lo4, hi4);
}

extern "C" void kernel_launch(void* const* d_in, const int* in_sizes, int n_in,
                              void* d_out, int out_size, void* d_ws, size_t ws_size,
                              hipStream_t stream) {
    (void)in_sizes; (void)n_in; (void)d_ws; (void)ws_size; (void)out_size;
    const float* x = (const float*)d_in[0];
    float* out = (float*)d_out;
    fused_dwt_kernel<<<dim3(4096), dim3(NT), 0, stream>>>(x, out);
}